// Round 6
// baseline (643.594 us; speedup 1.0000x reference)
//
#include <hip/hip_runtime.h>
#include <hip/hip_bf16.h>
#include <stdint.h>

// ---------------------------------------------------------------------------
// FiBiNet forward, MI355X (gfx950).  R8 = R7 with the A-staging register
// aliasing bug fixed.  R7 post-mortem: ALOAD_H(0) and ALOAD_H(1) both wrote
// ast[0..7]; ALOAD_H(1) was issued before AWRITE_H(0) consumed ast, so rows
// 0..127 of every A-tile got rows 128..255's data (absmax 0.27).  Fix: split
// register sets ast0/ast1 + reorder so each counted vmcnt drains exactly the
// intended 8 loads and 8 B-loads stay in flight across every barrier.
// fc0 still constructs A in-kernel from t1/t2 x x/xs2 (no feat pass).
// ---------------------------------------------------------------------------

typedef __attribute__((ext_vector_type(4))) int   int4v;
typedef __attribute__((ext_vector_type(4))) unsigned uint4v;
typedef __attribute__((ext_vector_type(4))) float f32x4;

__device__ __forceinline__ unsigned short f32_bf16(float f) {
  unsigned u = __builtin_bit_cast(unsigned, f);
  u = (u + 0x7fffu + ((u >> 16) & 1u)) >> 16;   // RNE
  return (unsigned short)u;
}
__device__ __forceinline__ unsigned pk_bf16(float lo, float hi) {
  return (unsigned)f32_bf16(lo) | ((unsigned)f32_bf16(hi) << 16);
}
__device__ __forceinline__ unsigned cvt_pk(float lo, float hi) {
  unsigned r;
  asm("v_cvt_pk_bf16_f32 %0, %1, %2" : "=v"(r) : "v"(lo), "v"(hi));
  return r;
}

// ------------------------------- SE block ----------------------------------
// Also writes xs2 = x * scale (threads already hold their x values).
__global__ __launch_bounds__(256) void se_kernel(
    const float* __restrict__ x, const float* __restrict__ w1,
    const float* __restrict__ w2, float* __restrict__ scale,
    float* __restrict__ xs2) {
  __shared__ float Z[32];
  __shared__ float A1[4];
  __shared__ float Sc[32];
  int b = blockIdx.x;
  int t = threadIdx.x;
  int f = t >> 3, sub = t & 7;
  const float4* xp = (const float4*)(x + (size_t)b * 2048 + f * 64 + sub * 8);
  float4 v0 = xp[0], v1 = xp[1];
  float s = v0.x + v0.y + v0.z + v0.w + v1.x + v1.y + v1.z + v1.w;
  s += __shfl_down(s, 4, 8);
  s += __shfl_down(s, 2, 8);
  s += __shfl_down(s, 1, 8);
  if (sub == 0) Z[f] = s * (1.0f / 64.0f);
  __syncthreads();
  if (t < 4) {
    float a = 0.f;
#pragma unroll
    for (int ff = 0; ff < 32; ++ff) a += Z[ff] * w1[t * 32 + ff];
    A1[t] = fmaxf(a, 0.f);
  }
  __syncthreads();
  if (t < 32) {
    float a = 0.f;
#pragma unroll
    for (int r = 0; r < 4; ++r) a += A1[r] * w2[t * 4 + r];
    float sg = 1.f / (1.f + expf(-a));
    scale[b * 32 + t] = sg;
    Sc[t] = sg;
  }
  __syncthreads();
  float sc = Sc[f];
  float4 o0, o1;
  o0.x = v0.x * sc; o0.y = v0.y * sc; o0.z = v0.z * sc; o0.w = v0.w * sc;
  o1.x = v1.x * sc; o1.y = v1.y * sc; o1.z = v1.z * sc; o1.w = v1.w * sc;
  float4* op = (float4*)(xs2 + (size_t)b * 2048 + f * 64 + sub * 8);
  op[0] = o0; op[1] = o1;
}

// -------------------- per-field bilinear transforms ------------------------
__global__ __launch_bounds__(256) void t_kernel(
    const float* __restrict__ x, const float* __restrict__ W1,
    const float* __restrict__ W2, const float* __restrict__ scale,
    float* __restrict__ t1, float* __restrict__ t2) {
  __shared__ float Wl[64 * 65];
  __shared__ float xs[64 * 65];
  int f = blockIdx.x;
  int b0 = blockIdx.y * 64;
  int which = blockIdx.z;
  const float* W = (which ? W2 : W1) + (size_t)f * 4096;
  float* tout = which ? t2 : t1;
  int t = threadIdx.x;
#pragma unroll
  for (int it = 0; it < 16; ++it) {
    int idx = it * 256 + t;
    int o = idx >> 6, e = idx & 63;
    Wl[o * 65 + e] = W[idx];
  }
#pragma unroll
  for (int it = 0; it < 16; ++it) {
    int idx = it * 256 + t;
    int bl = idx >> 6, e = idx & 63;
    float v = x[(size_t)(b0 + bl) * 2048 + f * 64 + e];
    if (which) v *= scale[(b0 + bl) * 32 + f];
    xs[bl * 65 + e] = v;
  }
  __syncthreads();
  int o = t & 63, g = t >> 6;
  float sum[16];
#pragma unroll
  for (int r = 0; r < 16; ++r) sum[r] = 0.f;
#pragma unroll 4
  for (int e = 0; e < 64; ++e) {
    float wv = Wl[o * 65 + e];
#pragma unroll
    for (int r = 0; r < 16; ++r) sum[r] += xs[(g * 16 + r) * 65 + e] * wv;
  }
#pragma unroll
  for (int r = 0; r < 16; ++r)
    tout[(size_t)(b0 + g * 16 + r) * 1984 + f * 64 + o] = sum[r];
}

// ------------------------------- MFMA GEMM ---------------------------------
__device__ __forceinline__ void mfma_bf16(f32x4& d, int4v a, int4v b) {
  asm volatile("v_mfma_f32_16x16x32_bf16 %0, %1, %2, %0"
               : "+v"(d) : "v"(a), "v"(b));
}

// ---- fc0 GEMM: 256x256 tile, BK=64, 512 thr (8 waves 2Mx4N), splitK=16.
// A constructed in-kernel: A[b, s*64+e] = t_sel[b,i,e] * x_sel[b,j,e].
#define FBM 256
#define FBN 256
#define FBK 64

__device__ __forceinline__ void fc0_phase(
    const unsigned short* sAb, const unsigned short* sBb,
    int kk, int wr, int wc, int l15, int l4, f32x4 (&acc)[8][4]) {
  int4v av[8], bv[4];
#pragma unroll
  for (int i = 0; i < 8; ++i) {
    int ar = wr + i * 16 + l15;
    av[i] = *(const int4v*)&sAb[(ar * 8 + ((kk * 4 + l4) ^ (ar & 7))) * 8];
  }
#pragma unroll
  for (int j = 0; j < 4; ++j) {
    int br = wc + j * 16 + l15;
    bv[j] = *(const int4v*)&sBb[(br * 8 + ((kk * 4 + l4) ^ (br & 7))) * 8];
  }
#pragma unroll
  for (int i = 0; i < 8; ++i)
#pragma unroll
    for (int j = 0; j < 4; ++j) mfma_bf16(acc[i][j], av[i], bv[j]);
}

__global__ __launch_bounds__(512, 2) void gemm_fc0(
    const float* __restrict__ T1, const float* __restrict__ T2,
    const float* __restrict__ X, const float* __restrict__ XS2,
    const float* __restrict__ Bp, float* __restrict__ Cp, int kz) {
  __shared__ unsigned short sA[2][FBM * FBK];  // 2 x 32 KB bf16
  __shared__ unsigned short sB[2][FBN * FBK];  // 2 x 32 KB bf16
  const int K = 63488;
  int tid = threadIdx.x;
  int lane = tid & 63;
  int wave = tid >> 6;
  // bid = s + 64*m, s = n + 4*z : the 4 m-blocks of one (n,z) share an XCD
  int bid = blockIdx.x;
  int m0 = (bid >> 6) << 8;
  int sb = bid & 63;
  int n0 = (sb & 3) << 8;
  int z  = sb >> 2;                // 0..15
  int wr = (wave >> 2) * 128, wc = (wave & 3) * 64;
  int l15 = lane & 15, l4 = lane >> 4;
  int kbase = z * kz;
  int s0 = kbase >> 6;             // first pair-index of this z-slice
  int nt = kz / FBK;               // 62

  f32x4 acc[8][4];
#pragma unroll
  for (int i = 0; i < 8; ++i)
#pragma unroll
    for (int j = 0; j < 4; ++j) acc[i][j] = (f32x4){0.f, 0.f, 0.f, 0.f};

  // per-thread staging maps: 2048 chunks of 16B per operand tile; 4/thread
  unsigned rtOff[4], rxOff[4], bOff[4]; int sDst[4];
#pragma unroll
  for (int it = 0; it < 4; ++it) {
    int c = it * 512 + tid;
    int r = c >> 3, l = c & 7;
    sDst[it] = (r * 8 + (l ^ (r & 7))) * 8;  // swizzled dest (shorts)
    rtOff[it] = (unsigned)(m0 + r) * 1984u + (unsigned)(l * 8);
    rxOff[it] = (unsigned)(m0 + r) * 2048u + (unsigned)(l * 8);
    bOff[it]  = (unsigned)(n0 + r) * (unsigned)K + (unsigned)(l * 8);
  }

  float4 ast0[8];    // A-source regs, half 0 (chunks it=0,1: rows 0..127)
  float4 ast1[8];    // A-source regs, half 1 (chunks it=2,3: rows 128..255)
  float4 bst[8];     // B-source regs
  const float* tpc = T1;
  const float* xpc = X;

  // uniform per-tile pair selection: s -> (which,i,j) -> base pointers
  auto set_pair = [&](int s) {
    int which = (s >= 496);
    int p = s - (which ? 496 : 0);
    int i = (int)((63.0f - sqrtf((float)(3969 - 8 * p))) * 0.5f);
    while ((i * (63 - i)) / 2 > p) --i;
    while (((i + 1) * (62 - i)) / 2 <= p) ++i;
    int j = i + 1 + (p - (i * (63 - i)) / 2);
    tpc = (which ? T2 : T1) + i * 64;
    xpc = (which ? XS2 : X) + j * 64;
  };

#define FC0_ALOAD0()                                                           \
  _Pragma("unroll") for (int it = 0; it < 2; ++it) {                           \
    ast0[it * 4 + 0] = *(const float4*)(tpc + rtOff[it]);                      \
    ast0[it * 4 + 1] = *(const float4*)(tpc + rtOff[it] + 4);                  \
    ast0[it * 4 + 2] = *(const float4*)(xpc + rxOff[it]);                      \
    ast0[it * 4 + 3] = *(const float4*)(xpc + rxOff[it] + 4);                  \
  }
#define FC0_ALOAD1()                                                           \
  _Pragma("unroll") for (int it = 2; it < 4; ++it) {                           \
    ast1[(it - 2) * 4 + 0] = *(const float4*)(tpc + rtOff[it]);                \
    ast1[(it - 2) * 4 + 1] = *(const float4*)(tpc + rtOff[it] + 4);            \
    ast1[(it - 2) * 4 + 2] = *(const float4*)(xpc + rxOff[it]);                \
    ast1[(it - 2) * 4 + 3] = *(const float4*)(xpc + rxOff[it] + 4);            \
  }
#define FC0_AWRITE0(buf)                                                       \
  _Pragma("unroll") for (int it = 0; it < 2; ++it) {                           \
    int q = it * 4;                                                            \
    uint4v o;                                                                  \
    o.x = cvt_pk(ast0[q].x * ast0[q + 2].x, ast0[q].y * ast0[q + 2].y);        \
    o.y = cvt_pk(ast0[q].z * ast0[q + 2].z, ast0[q].w * ast0[q + 2].w);        \
    o.z = cvt_pk(ast0[q + 1].x * ast0[q + 3].x, ast0[q + 1].y * ast0[q + 3].y);\
    o.w = cvt_pk(ast0[q + 1].z * ast0[q + 3].z, ast0[q + 1].w * ast0[q + 3].w);\
    *(uint4v*)(&sA[buf][sDst[it]]) = o;                                        \
  }
#define FC0_AWRITE1(buf)                                                       \
  _Pragma("unroll") for (int it = 2; it < 4; ++it) {                           \
    int q = (it - 2) * 4;                                                      \
    uint4v o;                                                                  \
    o.x = cvt_pk(ast1[q].x * ast1[q + 2].x, ast1[q].y * ast1[q + 2].y);        \
    o.y = cvt_pk(ast1[q].z * ast1[q + 2].z, ast1[q].w * ast1[q + 2].w);        \
    o.z = cvt_pk(ast1[q + 1].x * ast1[q + 3].x, ast1[q + 1].y * ast1[q + 3].y);\
    o.w = cvt_pk(ast1[q + 1].z * ast1[q + 3].z, ast1[q + 1].w * ast1[q + 3].w);\
    *(uint4v*)(&sA[buf][sDst[it]]) = o;                                        \
  }
#define FC0_BLOAD(kt)                                                          \
  _Pragma("unroll") for (int it = 0; it < 4; ++it) {                           \
    const float* gp = Bp + bOff[it] + (kt);                                    \
    bst[2 * it]     = *(const float4*)gp;                                      \
    bst[2 * it + 1] = *(const float4*)(gp + 4);                                \
  }
#define FC0_BWRITE(buf)                                                        \
  _Pragma("unroll") for (int it = 0; it < 4; ++it) {                           \
    uint4v o;                                                                  \
    o.x = cvt_pk(bst[2 * it].x, bst[2 * it].y);                                \
    o.y = cvt_pk(bst[2 * it].z, bst[2 * it].w);                                \
    o.z = cvt_pk(bst[2 * it + 1].x, bst[2 * it + 1].y);                        \
    o.w = cvt_pk(bst[2 * it + 1].z, bst[2 * it + 1].w);                        \
    *(uint4v*)(&sB[buf][sDst[it]]) = o;                                        \
  }
#define VMW(n) asm volatile("s_waitcnt vmcnt(" #n ")" ::: "memory")

  // ---- prologue (serial, once): build sA[0], sB[0]; B(t1) left in flight --
  set_pair(s0);
  FC0_ALOAD0()
  VMW(0);
  FC0_AWRITE0(0)
  FC0_ALOAD1()
  VMW(0);
  FC0_AWRITE1(0)
  FC0_BLOAD(kbase)
  VMW(0);
  FC0_BWRITE(0)
  FC0_BLOAD(kbase + FBK)          // 8 outstanding = B(tile1) [loop invariant]
  asm volatile("s_waitcnt lgkmcnt(0)" ::: "memory");
  __builtin_amdgcn_s_barrier();

// tile body: entry invariant = 8 outstanding (B(t+1) loads; bst = B(t+1)).
// Issue-order ledger (outstanding after each step):
//   ALOAD0: 16 -> vmcnt(8): B(t+1) regs done -> BWRITE
//   ALOAD1: 16 -> vmcnt(8): Ah0 done -> AWRITE0
//   BLOAD:  16 -> vmcnt(8): Ah1 done (8 remain = B(t+2)) -> AWRITE1
#define FC0_TILE(cur, nxt, SNEXT, KT2, DO_B)                                   \
  {                                                                            \
    fc0_phase(sA[cur], sB[cur], 0, wr, wc, l15, l4, acc);                      \
    set_pair(SNEXT);                                                           \
    FC0_ALOAD0()                                                               \
    VMW(8);                                                                    \
    FC0_BWRITE(nxt)                                                            \
    FC0_ALOAD1()                                                               \
    VMW(8);                                                                    \
    FC0_AWRITE0(nxt)                                                           \
    if (DO_B) { FC0_BLOAD(KT2) VMW(8); } else { VMW(0); }                      \
    FC0_AWRITE1(nxt)                                                           \
    fc0_phase(sA[cur], sB[cur], 1, wr, wc, l15, l4, acc);                      \
    asm volatile("s_waitcnt lgkmcnt(0)" ::: "memory");                         \
    __builtin_amdgcn_s_barrier();                                              \
  }

#pragma unroll 2
  for (int t = 0; t < nt - 2; ++t) {
    int cur = t & 1, nxt = cur ^ 1;
    FC0_TILE(cur, nxt, s0 + t + 1, kbase + (t + 2) * FBK, 1)
  }
  {
    int t = nt - 2, cur = t & 1, nxt = cur ^ 1;
    FC0_TILE(cur, nxt, s0 + t + 1, 0, 0)
  }
  {
    int cur = (nt - 1) & 1;
    fc0_phase(sA[cur], sB[cur], 0, wr, wc, l15, l4, acc);
    fc0_phase(sA[cur], sB[cur], 1, wr, wc, l15, l4, acc);
  }
#undef FC0_TILE
#undef FC0_ALOAD0
#undef FC0_ALOAD1
#undef FC0_AWRITE0
#undef FC0_AWRITE1
#undef FC0_BLOAD
#undef FC0_BWRITE
#undef VMW

  asm volatile("s_nop 7\n\ts_nop 7\n\ts_nop 7" ::: "memory");
  float* cp = Cp + (size_t)z * 1024 * 1024;
#pragma unroll
  for (int i = 0; i < 8; ++i) {
    int rbase = m0 + wr + i * 16 + l4 * 4;
#pragma unroll
    for (int j = 0; j < 4; ++j) {
      int cc = n0 + wc + j * 16 + l15;
#pragma unroll
      for (int r = 0; r < 4; ++r)
        cp[(size_t)(rbase + r) * 1024 + cc] = acc[i][j][r];
    }
  }
}

// ---- legacy GEMM (kept for fc1): 256x128 block tile, 4 waves, 2-barrier ----
#define BM 256
#define BN 128
#define BK 64

__global__ __launch_bounds__(256, 2) void gemm_bt(
    const unsigned short* __restrict__ A, const float* __restrict__ B,
    float* __restrict__ Cp, int M, int N, int K, int kz) {
  __shared__ unsigned short sA[BM * BK];   // 32 KB
  __shared__ unsigned short sB[BN * BK];   // 16 KB
  int tid = threadIdx.x;
  int lane = tid & 63, wave = tid >> 6;
  int n0 = blockIdx.x * BN, m0 = blockIdx.y * BM;
  int z = blockIdx.z;
  int wr = (wave >> 1) * 128, wc = (wave & 1) * 64;
  int l15 = lane & 15, l4 = lane >> 4;
  f32x4 acc[8][4];
#pragma unroll
  for (int i = 0; i < 8; ++i)
#pragma unroll
    for (int j = 0; j < 4; ++j) acc[i][j] = (f32x4){0.f, 0.f, 0.f, 0.f};

  int kend = z * kz + kz;
  for (int kt = z * kz; kt < kend; kt += BK) {
#pragma unroll
    for (int it = 0; it < 8; ++it) {
      int c = it * 256 + tid;
      int r = c >> 3, p = c & 7;
      int gcol = (p ^ (r & 7)) * 8;
      const unsigned short* gp = A + (size_t)(m0 + r) * K + kt + gcol;
      __builtin_amdgcn_global_load_lds(
          (const __attribute__((address_space(1))) void*)gp,
          (__attribute__((address_space(3))) void*)(&sA[c * 8]), 16, 0, 0);
    }
#pragma unroll
    for (int it = 0; it < 4; ++it) {
      int c = it * 256 + tid;
      int r = c >> 3, l = c & 7;
      const float* gp = B + (size_t)(n0 + r) * K + kt + l * 8;
      float4 f0 = *(const float4*)gp;
      float4 f1 = *(const float4*)(gp + 4);
      uint4v q;
      q.x = pk_bf16(f0.x, f0.y); q.y = pk_bf16(f0.z, f0.w);
      q.z = pk_bf16(f1.x, f1.y); q.w = pk_bf16(f1.z, f1.w);
      int p = l ^ (r & 7);
      *(uint4v*)(&sB[(r * 8 + p) * 8]) = q;
    }
    __syncthreads();
#pragma unroll
    for (int kk = 0; kk < 2; ++kk) {
      int lc = kk * 4 + l4;
      int4v av[8], bv[4];
#pragma unroll
      for (int i = 0; i < 8; ++i) {
        int ar = wr + i * 16 + l15;
        av[i] = *(const int4v*)&sA[(ar * 8 + (lc ^ (ar & 7))) * 8];
      }
#pragma unroll
      for (int j = 0; j < 4; ++j) {
        int br = wc + j * 16 + l15;
        bv[j] = *(const int4v*)&sB[(br * 8 + (lc ^ (br & 7))) * 8];
      }
#pragma unroll
      for (int i = 0; i < 8; ++i)
#pragma unroll
        for (int j = 0; j < 4; ++j) mfma_bf16(acc[i][j], av[i], bv[j]);
    }
    __syncthreads();
  }
  asm volatile("s_nop 7\n\ts_nop 7\n\ts_nop 7" ::: "memory");
  float* cp = Cp + (size_t)z * M * N;
#pragma unroll
  for (int i = 0; i < 8; ++i) {
    int rbase = m0 + wr + i * 16 + l4 * 4;
#pragma unroll
    for (int j = 0; j < 4; ++j) {
      int cc = n0 + wc + j * 16 + l15;
#pragma unroll
      for (int r = 0; r < 4; ++r)
        cp[(size_t)(rbase + r) * N + cc] = acc[i][j][r];
    }
  }
}

// --------------------- splitK reduce + bias + relu -------------------------
__global__ __launch_bounds__(256) void reduce_bias_act(
    const float* __restrict__ parts, const float* __restrict__ bias,
    int MN, int nmask, int nz, unsigned short* __restrict__ out_bf,
    float* __restrict__ out_f) {
  int idx = blockIdx.x * 256 + threadIdx.x;
  if (idx >= MN) return;
  float s = 0.f;
  for (int z = 0; z < nz; ++z) s += parts[(size_t)z * MN + idx];
  s += bias[idx & nmask];
  s = fmaxf(s, 0.f);
  if (out_bf) out_bf[idx] = f32_bf16(s);
  else out_f[idx] = s;
}

// ------------------------------ fc2 + sigmoid ------------------------------
__global__ __launch_bounds__(256) void fc2_kernel(
    const float* __restrict__ h2, const float* __restrict__ w,
    const float* __restrict__ b, float* __restrict__ out) {
  int wave = threadIdx.x >> 6, lane = threadIdx.x & 63;
  int row = blockIdx.x * 4 + wave;
  const float4* hp = (const float4*)(h2 + (size_t)row * 512);
  const float4* wp = (const float4*)w;
  int i0 = lane * 2;
  float4 a0 = hp[i0], a1 = hp[i0 + 1];
  float4 w0 = wp[i0], w1 = wp[i0 + 1];
  float s = a0.x * w0.x + a0.y * w0.y + a0.z * w0.z + a0.w * w0.w +
            a1.x * w1.x + a1.y * w1.y + a1.z * w1.z + a1.w * w1.w;
#pragma unroll
  for (int off = 32; off > 0; off >>= 1) s += __shfl_down(s, off);
  if (lane == 0) out[row] = 1.f / (1.f + expf(-(s + b[0])));
}

// ---------------------------------------------------------------------------
extern "C" void kernel_launch(void* const* d_in, const int* in_sizes, int n_in,
                              void* d_out, int out_size, void* d_ws, size_t ws_size,
                              hipStream_t stream) {
  const float* x     = (const float*)d_in[0];
  const float* Wb1   = (const float*)d_in[1];
  const float* Wb2   = (const float*)d_in[2];
  const float* se_w1 = (const float*)d_in[3];
  const float* se_w2 = (const float*)d_in[4];
  const float* fc0_w = (const float*)d_in[5];
  const float* fc0_b = (const float*)d_in[6];
  const float* fc1_w = (const float*)d_in[7];
  const float* fc1_b = (const float*)d_in[8];
  const float* fc2_w = (const float*)d_in[9];
  const float* fc2_b = (const float*)d_in[10];
  (void)in_sizes; (void)n_in; (void)out_size; (void)ws_size;

  char* ws = (char*)d_ws;
  float*          scale = (float*)(ws + 0);                   //  128 KB
  float*          t1    = (float*)(ws + 131072);              //  7.75 MB
  float*          t2    = (float*)(ws + 8257536);             //  7.75 MB
  float*          xs2   = (float*)(ws + 16384000);            //  8 MB
  float*          hp    = (float*)(ws + 24772608);            //  64 MB partials
  unsigned short* h1b   = (unsigned short*)(ws + 91881472);   //  2 MB bf16
  float*          h2    = (float*)(ws + 93978624);            //  2 MB
  float*          out   = (float*)d_out;

  se_kernel<<<1024, 256, 0, stream>>>(x, se_w1, se_w2, scale, xs2);
  t_kernel<<<dim3(31, 16, 2), 256, 0, stream>>>(x, Wb1, Wb2, scale, t1, t2);
  // fc0: M=1024 N=1024 K=63488, splitK=16 (kz=3968 = 62 k-tiles), 256 blocks
  // A constructed in-kernel from t1/t2 x x/xs2 -> no feat materialization.
  gemm_fc0<<<256, 512, 0, stream>>>(t1, t2, x, xs2, fc0_w, hp, 3968);
  reduce_bias_act<<<4096, 256, 0, stream>>>(hp, fc0_b, 1024 * 1024, 1023, 16, h1b, nullptr);
  // fc1: M=1024 N=512 K=1024, splitK=16 (kz=64)
  gemm_bt<<<dim3(4, 4, 16), 256, 0, stream>>>(h1b, fc1_w, hp, 1024, 512, 1024, 64);
  reduce_bias_act<<<2048, 256, 0, stream>>>(hp, fc1_b, 1024 * 512, 511, 16, nullptr, h2);
  fc2_kernel<<<256, 256, 0, stream>>>(h2, fc2_w, fc2_b, out);
}

// Round 7
// 602.990 us; speedup vs baseline: 1.0673x; 1.0673x over previous
//
#include <hip/hip_runtime.h>
#include <hip/hip_bf16.h>
#include <stdint.h>

// ---------------------------------------------------------------------------
// FiBiNet forward, MI355X (gfx950).  R9 = R5 base (feat materialized; best
// measured 537us) with fc0's K-loop replaced by a FAITHFUL 4-phase (8-barrier)
// schedule.  R6's failed attempt differed in 3 ways, fixed here: (1) static
// sA[cur] indices via unroll-2 (R6 used runtime swapped pointers); (2) P1
// reads issued BEFORE ds_writes + counted lgkmcnt(8) (R6's lgkmcnt(0) waited
// on the 8 sB[nxt] writes every tile); (3) exact vmcnt ledger: entry/exit
// invariant 8 outstanding (B-reg loads), vmcnt(4)@P1 drains B regs,
// vmcnt(8)@P3 drains A-DMA inside the MFMA shadow.
// R8 post-mortem: in-kernel A-construction re-read t/x slices 4x across
// XCDs (FETCH 381->935 MB, fc0 316us) -> feat materialization restored.
// ---------------------------------------------------------------------------

typedef __attribute__((ext_vector_type(4))) int   int4v;
typedef __attribute__((ext_vector_type(4))) unsigned uint4v;
typedef __attribute__((ext_vector_type(4))) float f32x4;

__device__ __forceinline__ unsigned short f32_bf16(float f) {
  unsigned u = __builtin_bit_cast(unsigned, f);
  u = (u + 0x7fffu + ((u >> 16) & 1u)) >> 16;   // RNE
  return (unsigned short)u;
}
__device__ __forceinline__ unsigned pk_bf16(float lo, float hi) {
  return (unsigned)f32_bf16(lo) | ((unsigned)f32_bf16(hi) << 16);
}
__device__ __forceinline__ unsigned cvt_pk(float lo, float hi) {
  unsigned r;
  asm("v_cvt_pk_bf16_f32 %0, %1, %2" : "=v"(r) : "v"(lo), "v"(hi));
  return r;
}

// ------------------------------- SE block ----------------------------------
__global__ __launch_bounds__(256) void se_kernel(
    const float* __restrict__ x, const float* __restrict__ w1,
    const float* __restrict__ w2, float* __restrict__ scale) {
  __shared__ float Z[32];
  __shared__ float A1[4];
  int b = blockIdx.x;
  int t = threadIdx.x;
  int f = t >> 3, sub = t & 7;
  const float4* xp = (const float4*)(x + (size_t)b * 2048 + f * 64 + sub * 8);
  float4 v0 = xp[0], v1 = xp[1];
  float s = v0.x + v0.y + v0.z + v0.w + v1.x + v1.y + v1.z + v1.w;
  s += __shfl_down(s, 4, 8);
  s += __shfl_down(s, 2, 8);
  s += __shfl_down(s, 1, 8);
  if (sub == 0) Z[f] = s * (1.0f / 64.0f);
  __syncthreads();
  if (t < 4) {
    float a = 0.f;
#pragma unroll
    for (int ff = 0; ff < 32; ++ff) a += Z[ff] * w1[t * 32 + ff];
    A1[t] = fmaxf(a, 0.f);
  }
  __syncthreads();
  if (t < 32) {
    float a = 0.f;
#pragma unroll
    for (int r = 0; r < 4; ++r) a += A1[r] * w2[t * 4 + r];
    scale[b * 32 + t] = 1.f / (1.f + expf(-a));
  }
}

// -------------------- per-field bilinear transforms ------------------------
__global__ __launch_bounds__(256) void t_kernel(
    const float* __restrict__ x, const float* __restrict__ W1,
    const float* __restrict__ W2, const float* __restrict__ scale,
    float* __restrict__ t1, float* __restrict__ t2) {
  __shared__ float Wl[64 * 65];
  __shared__ float xs[64 * 65];
  int f = blockIdx.x;
  int b0 = blockIdx.y * 64;
  int which = blockIdx.z;
  const float* W = (which ? W2 : W1) + (size_t)f * 4096;
  float* tout = which ? t2 : t1;
  int t = threadIdx.x;
#pragma unroll
  for (int it = 0; it < 16; ++it) {
    int idx = it * 256 + t;
    int o = idx >> 6, e = idx & 63;
    Wl[o * 65 + e] = W[idx];
  }
#pragma unroll
  for (int it = 0; it < 16; ++it) {
    int idx = it * 256 + t;
    int bl = idx >> 6, e = idx & 63;
    float v = x[(size_t)(b0 + bl) * 2048 + f * 64 + e];
    if (which) v *= scale[(b0 + bl) * 32 + f];
    xs[bl * 65 + e] = v;
  }
  __syncthreads();
  int o = t & 63, g = t >> 6;
  float sum[16];
#pragma unroll
  for (int r = 0; r < 16; ++r) sum[r] = 0.f;
#pragma unroll 4
  for (int e = 0; e < 64; ++e) {
    float wv = Wl[o * 65 + e];
#pragma unroll
    for (int r = 0; r < 16; ++r) sum[r] += xs[(g * 16 + r) * 65 + e] * wv;
  }
#pragma unroll
  for (int r = 0; r < 16; ++r)
    tout[(size_t)(b0 + g * 16 + r) * 1984 + f * 64 + o] = sum[r];
}

// ----------------------- pair feature materialization ----------------------
__global__ __launch_bounds__(256) void feat_kernel(
    const float* __restrict__ x, const float* __restrict__ t1,
    const float* __restrict__ t2, const float* __restrict__ scale,
    unsigned short* __restrict__ feat) {
  int gid = blockIdx.x * 256 + threadIdx.x;
  int b = gid / 7936;
  int rem = gid - b * 7936;
  int s = rem >> 3;
  int e0 = (rem & 7) * 8;
  int which = (s >= 496) ? 1 : 0;
  int p = s - (which ? 496 : 0);
  int i = (int)((63.0f - sqrtf((float)(3969 - 8 * p))) * 0.5f);
  while ((i * (63 - i)) / 2 > p) --i;
  while (((i + 1) * (62 - i)) / 2 <= p) ++i;
  int j = i + 1 + (p - (i * (63 - i)) / 2);
  const float* tp = (which ? t2 : t1) + (size_t)b * 1984 + i * 64 + e0;
  const float* xp = x + (size_t)b * 2048 + j * 64 + e0;
  float sc = which ? scale[b * 32 + j] : 1.0f;
  float4 ta = *(const float4*)tp, tb = *(const float4*)(tp + 4);
  float4 xa = *(const float4*)xp, xb = *(const float4*)(xp + 4);
  uint4v o;
  o.x = pk_bf16(ta.x * xa.x * sc, ta.y * xa.y * sc);
  o.y = pk_bf16(ta.z * xa.z * sc, ta.w * xa.w * sc);
  o.z = pk_bf16(tb.x * xb.x * sc, tb.y * xb.y * sc);
  o.w = pk_bf16(tb.z * xb.z * sc, tb.w * xb.w * sc);
  *(uint4v*)(feat + (size_t)b * 63488 + s * 64 + e0) = o;
}

// ------------------------------- MFMA GEMM ---------------------------------
__device__ __forceinline__ void mfma_bf16(f32x4& d, int4v a, int4v b) {
  asm volatile("v_mfma_f32_16x16x32_bf16 %0, %1, %2, %0"
               : "+v"(d) : "v"(a), "v"(b));
}

// ---- fc0 pipeline GEMM: 256x256 tile, BK=64, 512 thr (8 waves 2Mx4N).
#define FBM 256
#define FBN 256
#define FBK 64

__device__ __forceinline__ void fc0_read_av(
    const unsigned short* sAb, int kk, int wr, int l15, int l4, int4v (&av)[8]) {
#pragma unroll
  for (int i = 0; i < 8; ++i) {
    int ar = wr + i * 16 + l15;
    av[i] = *(const int4v*)&sAb[(ar * 8 + ((kk * 4 + l4) ^ (ar & 7))) * 8];
  }
}
__device__ __forceinline__ void fc0_read_bv(
    const unsigned short* sBb, int kk, int j0, int wc, int l15, int l4,
    int4v (&bv)[2]) {
#pragma unroll
  for (int j = 0; j < 2; ++j) {
    int br = wc + (j0 + j) * 16 + l15;
    bv[j] = *(const int4v*)&sBb[(br * 8 + ((kk * 4 + l4) ^ (br & 7))) * 8];
  }
}
__device__ __forceinline__ void fc0_mfma8x2(
    f32x4 (&acc)[8][4], int j0, int4v (&av)[8], int4v (&bv)[2]) {
  __builtin_amdgcn_s_setprio(1);
#pragma unroll
  for (int i = 0; i < 8; ++i)
#pragma unroll
    for (int j = 0; j < 2; ++j) mfma_bf16(acc[i][j0 + j], av[i], bv[j]);
  __builtin_amdgcn_s_setprio(0);
}

__global__ __launch_bounds__(512, 2) void gemm_fc0(
    const unsigned short* __restrict__ A, const float* __restrict__ Bp,
    float* __restrict__ Cp, int M, int N, int K, int kz) {
  __shared__ unsigned short sA[2][FBM * FBK];  // 2 x 32 KB bf16
  __shared__ unsigned short sB[2][FBN * FBK];  // 2 x 32 KB bf16
  int tid = threadIdx.x;
  int lane = tid & 63;
  int wave = tid >> 6;
  // bid = s + 64*m, s = n + 4*z : the 4 m-blocks of one (n,z) share an XCD
  int bid = blockIdx.x;
  int m0 = (bid >> 6) << 8;
  int sb = bid & 63;
  int n0 = (sb & 3) << 8;
  int z  = sb >> 2;                // 0..15
  int wr = (wave >> 2) * 128, wc = (wave & 3) * 64;
  int l15 = lane & 15, l4 = lane >> 4;
  int kbase = z * kz;
  int nt = kz / FBK;               // 62

  f32x4 acc[8][4];
#pragma unroll
  for (int i = 0; i < 8; ++i)
#pragma unroll
    for (int j = 0; j < 4; ++j) acc[i][j] = (f32x4){0.f, 0.f, 0.f, 0.f};

  // staging maps: 2048 chunks of 16B out per operand; 4 chunks/thread
  unsigned aOff[4]; int aDst[4];
  unsigned bOff[4]; int bDst[4];
#pragma unroll
  for (int it = 0; it < 4; ++it) {
    int c = it * 512 + tid;
    int r = c >> 3, l = c & 7;
    aOff[it] = (unsigned)(m0 + r) * (unsigned)K + (unsigned)((l ^ (r & 7)) << 3);
    aDst[it] = c * 8;                       // shorts (16B chunks, linear)
    bOff[it] = (unsigned)(n0 + r) * (unsigned)K + (unsigned)(l << 3);
    bDst[it] = (r * 8 + (l ^ (r & 7))) * 8; // shorts (swizzled dest)
  }

#define FC0_STAGE_A(buf, kt)                                                   \
  _Pragma("unroll") for (int it = 0; it < 4; ++it) {                           \
    __builtin_amdgcn_global_load_lds(                                          \
        (const __attribute__((address_space(1))) void*)(A + aOff[it] + (kt)),  \
        (__attribute__((address_space(3))) void*)(&sA[buf][aDst[it]]), 16, 0, 0); \
  }
#define FC0_LOAD_B(kt)                                                         \
  _Pragma("unroll") for (int it = 0; it < 4; ++it) {                           \
    const float* gp = Bp + bOff[it] + (kt);                                    \
    bst[2 * it]     = *(const float4*)gp;                                      \
    bst[2 * it + 1] = *(const float4*)(gp + 4);                                \
  }
#define FC0_WRITE_B(buf)                                                       \
  _Pragma("unroll") for (int it = 0; it < 4; ++it) {                           \
    uint4v q;                                                                  \
    q.x = cvt_pk(bst[2 * it].x, bst[2 * it].y);                                \
    q.y = cvt_pk(bst[2 * it].z, bst[2 * it].w);                                \
    q.z = cvt_pk(bst[2 * it + 1].x, bst[2 * it + 1].y);                        \
    q.w = cvt_pk(bst[2 * it + 1].z, bst[2 * it + 1].w);                        \
    *(uint4v*)(&sB[buf][bDst[it]]) = q;                                        \
  }
#define BAR() __builtin_amdgcn_s_barrier()

// One K-tile = 4 phases (kk x j-half), 2 barriers each.  vmcnt ledger
// (per-wave outstanding), entry invariant = 8 (B(t+1) reg-loads):
//   P0: +4 A-DMA -> 12.             P1: vmcnt(4) drains B regs (A-DMA stays).
//   P2: +8 B(t+2) loads -> 12.      P3: W_FIN=vmcnt(8) drains A-DMA -> 8.
// lgkm: P1 reads bv FIRST then 8 ds_writes -> counted lgkmcnt(8) (in-order).
#define FC0_TILE(cur, nxt, KT1, KT2, DO_STAGE, DO_B, W_P1, W_FIN)              \
  {                                                                            \
    /* P0: kk0 j01 */                                                          \
    fc0_read_av(sA[cur], 0, wr, l15, l4, av);                                  \
    fc0_read_bv(sB[cur], 0, 0, wc, l15, l4, bv);                               \
    if (DO_STAGE) { FC0_STAGE_A(nxt, KT1) }                                    \
    BAR();                                                                     \
    asm volatile("s_waitcnt lgkmcnt(0)" ::: "memory");                         \
    fc0_mfma8x2(acc, 0, av, bv);                                               \
    BAR();                                                                     \
    /* P1: kk0 j23 */                                                          \
    fc0_read_bv(sB[cur], 0, 2, wc, l15, l4, bv);                               \
    if (DO_STAGE) {                                                            \
      asm volatile("s_waitcnt vmcnt(4)" ::: "memory");                         \
      FC0_WRITE_B(nxt)                                                         \
    }                                                                          \
    BAR();                                                                     \
    asm volatile("s_waitcnt " W_P1 ::: "memory");                              \
    fc0_mfma8x2(acc, 2, av, bv);                                               \
    BAR();                                                                     \
    /* P2: kk1 j01 */                                                          \
    fc0_read_av(sA[cur], 1, wr, l15, l4, av);                                  \
    fc0_read_bv(sB[cur], 1, 0, wc, l15, l4, bv);                               \
    if (DO_B) { FC0_LOAD_B(KT2) }                                              \
    BAR();                                                                     \
    asm volatile("s_waitcnt lgkmcnt(0)" ::: "memory");                         \
    fc0_mfma8x2(acc, 0, av, bv);                                               \
    BAR();                                                                     \
    /* P3: kk1 j23 */                                                          \
    fc0_read_bv(sB[cur], 1, 2, wc, l15, l4, bv);                               \
    BAR();                                                                     \
    asm volatile("s_waitcnt lgkmcnt(0)" ::: "memory");                         \
    fc0_mfma8x2(acc, 2, av, bv);                                               \
    asm volatile("s_waitcnt " W_FIN ::: "memory");                             \
    BAR();                                                                     \
  }

  float4 bst[8];
  int4v av[8], bv[2];
  // ---- prologue: B0->regs->sB[0]; A0 DMA->sA[0]; B1->regs (8 in flight) ----
  FC0_LOAD_B(kbase)
  asm volatile("s_waitcnt vmcnt(0)" ::: "memory");
  FC0_WRITE_B(0)
  FC0_STAGE_A(0, kbase)                   // +4 A-DMA
  FC0_LOAD_B(kbase + FBK)                 // +8 -> 12
  asm volatile("s_waitcnt vmcnt(8) lgkmcnt(0)" ::: "memory");  // A0 done
  BAR();

#pragma unroll 2
  for (int t = 0; t < nt - 2; ++t) {
    int cur = t & 1, nxt = cur ^ 1;
    FC0_TILE(cur, nxt, kbase + (t + 1) * FBK, kbase + (t + 2) * FBK,
             1, 1, "lgkmcnt(8)", "vmcnt(8)")
  }
  {  // t = nt-2: stage/publish last tile, no B(t+2); drain A fully
    int t = nt - 2, cur = t & 1, nxt = cur ^ 1;
    FC0_TILE(cur, nxt, kbase + (nt - 1) * FBK, 0, 1, 0,
             "lgkmcnt(8)", "vmcnt(0)")
  }
  {  // t = nt-1: pure compute
    int cur = (nt - 1) & 1, nxt = cur ^ 1;
    (void)nxt;
    FC0_TILE(cur, nxt, 0, 0, 0, 0, "lgkmcnt(0)", "vmcnt(0)")
  }
#undef FC0_TILE
#undef FC0_STAGE_A
#undef FC0_LOAD_B
#undef FC0_WRITE_B
#undef BAR

  asm volatile("s_nop 7\n\ts_nop 7\n\ts_nop 7" ::: "memory");
  float* cp = Cp + (size_t)z * M * N;
#pragma unroll
  for (int i = 0; i < 8; ++i) {
    int rbase = m0 + wr + i * 16 + l4 * 4;
#pragma unroll
    for (int j = 0; j < 4; ++j) {
      int cc = n0 + wc + j * 16 + l15;
#pragma unroll
      for (int r = 0; r < 4; ++r)
        cp[(size_t)(rbase + r) * N + cc] = acc[i][j][r];
    }
  }
}

// ---- legacy GEMM (kept for fc1): 256x128 block tile, 4 waves, 2-barrier ----
#define BM 256
#define BN 128
#define BK 64

__global__ __launch_bounds__(256, 2) void gemm_bt(
    const unsigned short* __restrict__ A, const float* __restrict__ B,
    float* __restrict__ Cp, int M, int N, int K, int kz) {
  __shared__ unsigned short sA[BM * BK];   // 32 KB
  __shared__ unsigned short sB[BN * BK];   // 16 KB
  int tid = threadIdx.x;
  int lane = tid & 63, wave = tid >> 6;
  int n0 = blockIdx.x * BN, m0 = blockIdx.y * BM;
  int z = blockIdx.z;
  int wr = (wave >> 1) * 128, wc = (wave & 1) * 64;
  int l15 = lane & 15, l4 = lane >> 4;
  f32x4 acc[8][4];
#pragma unroll
  for (int i = 0; i < 8; ++i)
#pragma unroll
    for (int j = 0; j < 4; ++j) acc[i][j] = (f32x4){0.f, 0.f, 0.f, 0.f};

  int kend = z * kz + kz;
  for (int kt = z * kz; kt < kend; kt += BK) {
#pragma unroll
    for (int it = 0; it < 8; ++it) {
      int c = it * 256 + tid;
      int r = c >> 3, p = c & 7;
      int gcol = (p ^ (r & 7)) * 8;
      const unsigned short* gp = A + (size_t)(m0 + r) * K + kt + gcol;
      __builtin_amdgcn_global_load_lds(
          (const __attribute__((address_space(1))) void*)gp,
          (__attribute__((address_space(3))) void*)(&sA[c * 8]), 16, 0, 0);
    }
#pragma unroll
    for (int it = 0; it < 4; ++it) {
      int c = it * 256 + tid;
      int r = c >> 3, l = c & 7;
      const float* gp = B + (size_t)(n0 + r) * K + kt + l * 8;
      float4 f0 = *(const float4*)gp;
      float4 f1 = *(const float4*)(gp + 4);
      uint4v q;
      q.x = pk_bf16(f0.x, f0.y); q.y = pk_bf16(f0.z, f0.w);
      q.z = pk_bf16(f1.x, f1.y); q.w = pk_bf16(f1.z, f1.w);
      int p = l ^ (r & 7);
      *(uint4v*)(&sB[(r * 8 + p) * 8]) = q;
    }
    __syncthreads();
#pragma unroll
    for (int kk = 0; kk < 2; ++kk) {
      int lc = kk * 4 + l4;
      int4v av[8], bv[4];
#pragma unroll
      for (int i = 0; i < 8; ++i) {
        int ar = wr + i * 16 + l15;
        av[i] = *(const int4v*)&sA[(ar * 8 + (lc ^ (ar & 7))) * 8];
      }
#pragma unroll
      for (int j = 0; j < 4; ++j) {
        int br = wc + j * 16 + l15;
        bv[j] = *(const int4v*)&sB[(br * 8 + (lc ^ (br & 7))) * 8];
      }
#pragma unroll
      for (int i = 0; i < 8; ++i)
#pragma unroll
        for (int j = 0; j < 4; ++j) mfma_bf16(acc[i][j], av[i], bv[j]);
    }
    __syncthreads();
  }
  asm volatile("s_nop 7\n\ts_nop 7\n\ts_nop 7" ::: "memory");
  float* cp = Cp + (size_t)z * M * N;
#pragma unroll
  for (int i = 0; i < 8; ++i) {
    int rbase = m0 + wr + i * 16 + l4 * 4;
#pragma unroll
    for (int j = 0; j < 4; ++j) {
      int cc = n0 + wc + j * 16 + l15;
#pragma unroll
      for (int r = 0; r < 4; ++r)
        cp[(size_t)(rbase + r) * N + cc] = acc[i][j][r];
    }
  }
}

// --------------------- splitK reduce + bias + relu -------------------------
__global__ __launch_bounds__(256) void reduce_bias_act(
    const float* __restrict__ parts, const float* __restrict__ bias,
    int MN, int nmask, int nz, unsigned short* __restrict__ out_bf,
    float* __restrict__ out_f) {
  int idx = blockIdx.x * 256 + threadIdx.x;
  if (idx >= MN) return;
  float s = 0.f;
  for (int z = 0; z < nz; ++z) s += parts[(size_t)z * MN + idx];
  s += bias[idx & nmask];
  s = fmaxf(s, 0.f);
  if (out_bf) out_bf[idx] = f32_bf16(s);
  else out_f[idx] = s;
}

// ------------------------------ fc2 + sigmoid ------------------------------
__global__ __launch_bounds__(256) void fc2_kernel(
    const float* __restrict__ h2, const float* __restrict__ w,
    const float* __restrict__ b, float* __restrict__ out) {
  int wave = threadIdx.x >> 6, lane = threadIdx.x & 63;
  int row = blockIdx.x * 4 + wave;
  const float4* hp = (const float4*)(h2 + (size_t)row * 512);
  const float4* wp = (const float4*)w;
  int i0 = lane * 2;
  float4 a0 = hp[i0], a1 = hp[i0 + 1];
  float4 w0 = wp[i0], w1 = wp[i0 + 1];
  float s = a0.x * w0.x + a0.y * w0.y + a0.z * w0.z + a0.w * w0.w +
            a1.x * w1.x + a1.y * w1.y + a1.z * w1.z + a1.w * w1.w;
#pragma unroll
  for (int off = 32; off > 0; off >>= 1) s += __shfl_down(s, off);
  if (lane == 0) out[row] = 1.f / (1.f + expf(-(s + b[0])));
}

// ---------------------------------------------------------------------------
extern "C" void kernel_launch(void* const* d_in, const int* in_sizes, int n_in,
                              void* d_out, int out_size, void* d_ws, size_t ws_size,
                              hipStream_t stream) {
  const float* x     = (const float*)d_in[0];
  const float* Wb1   = (const float*)d_in[1];
  const float* Wb2   = (const float*)d_in[2];
  const float* se_w1 = (const float*)d_in[3];
  const float* se_w2 = (const float*)d_in[4];
  const float* fc0_w = (const float*)d_in[5];
  const float* fc0_b = (const float*)d_in[6];
  const float* fc1_w = (const float*)d_in[7];
  const float* fc1_b = (const float*)d_in[8];
  const float* fc2_w = (const float*)d_in[9];
  const float* fc2_b = (const float*)d_in[10];
  (void)in_sizes; (void)n_in; (void)out_size; (void)ws_size;

  char* ws = (char*)d_ws;
  float*          scale = (float*)(ws + 0);                   //  128 KB
  float*          t1    = (float*)(ws + 131072);              //  7.75 MB
  float*          t2    = (float*)(ws + 8257536);             //  7.75 MB
  unsigned short* feat  = (unsigned short*)(ws + 16384000);   //  124 MB bf16
  float*          hp    = (float*)(ws + 146407424);           //  64 MB partials
  unsigned short* h1b   = (unsigned short*)(ws + 213516288);  //  2 MB bf16
  float*          h2    = (float*)(ws + 215613440);           //  2 MB
  float*          out   = (float*)d_out;

  se_kernel<<<1024, 256, 0, stream>>>(x, se_w1, se_w2, scale);
  t_kernel<<<dim3(31, 16, 2), 256, 0, stream>>>(x, Wb1, Wb2, scale, t1, t2);
  feat_kernel<<<31744, 256, 0, stream>>>(x, t1, t2, scale, feat);
  // fc0: M=1024 N=1024 K=63488, splitK=16 (kz=3968 = 62 k-tiles), 256 blocks
  gemm_fc0<<<256, 512, 0, stream>>>(feat, fc0_w, hp, 1024, 1024, 63488, 3968);
  reduce_bias_act<<<4096, 256, 0, stream>>>(hp, fc0_b, 1024 * 1024, 1023, 16, h1b, nullptr);
  // fc1: M=1024 N=512 K=1024, splitK=16 (kz=64)
  gemm_bt<<<dim3(4, 4, 16), 256, 0, stream>>>(h1b, fc1_w, hp, 1024, 512, 1024, 64);
  reduce_bias_act<<<2048, 256, 0, stream>>>(hp, fc1_b, 1024 * 512, 511, 16, nullptr, h2);
  fc2_kernel<<<256, 256, 0, stream>>>(h2, fc2_w, fc2_b, out);
}